// Round 10
// baseline (192.573 us; speedup 1.0000x reference)
//
#include <hip/hip_runtime.h>
#include <math.h>

#define S_ 2048
#define D_ 1024
#define HN_ 1024
#define B_ 4
#define M_ 8192
#define ITERS_ 10
#define DT_ 0.1f
#define PI_ 3.14159265358979323846f
#define TWOPI_ 6.28318530717958647692f
#define INV2PI_ 0.15915494309189533577f
#define SCALE_ 4096.0f
#define INVSC2_ (1.0f / 16777216.0f)   // 2^-24

typedef __attribute__((ext_vector_type(8))) _Float16 f16x8;
typedef __attribute__((ext_vector_type(4))) float f32x4;

// static scratch
__device__ __align__(16) ushort g_xs [(size_t)M_ * 2048];   // x split [a|b] fp16, scaled 4096
__device__ __align__(16) ushort g_WpT[(size_t)HN_ * 2048];  // Wp^T split [a|b] fp16, scaled
__device__ __align__(16) ushort g_WoT[(size_t)D_ * 1024];   // Wo^T fp16 [d][hn]
__device__ __align__(16) float  g_ph [(size_t)B_ * HN_ * S_]; // phases f32 [b][hn][s]
__device__ __align__(16) ushort g_phh[(size_t)B_ * HN_ * S_]; // final phases fp16
__device__ __align__(16) ushort g_phT[(size_t)M_ * HN_];      // phases fp16 [(b,s)][hn]

__device__ __forceinline__ ushort f2h(float f) {
    union { _Float16 h; ushort u; } v; v.h = (_Float16)f; return v.u;
}
__device__ __forceinline__ void split2s(float x, ushort& A, ushort& Bc) {
    const float xs = x * SCALE_;
    union { _Float16 h; ushort u; } va, vb;
    va.h = (_Float16)xs;
    const float r = xs - (float)va.h;   // exact
    vb.h = (_Float16)r;
    A = va.u; Bc = vb.u;
}
__device__ __forceinline__ void gload16(const void* g, void* l) {
    __builtin_amdgcn_global_load_lds(
        (const __attribute__((address_space(1))) void*)g,
        (__attribute__((address_space(3))) void*)l, 16, 0, 0);
}
__device__ __forceinline__ int pack2(ushort a, ushort b) {
    return (int)(unsigned)a | ((int)(unsigned)b << 16);
}

// ---------------------------------------------------------------------------
// x [8192][1024] f32 -> g_xs [8192][2048] fp16: [k: a][1024+k: b]
// ---------------------------------------------------------------------------
__global__ __launch_bounds__(256) void split_x(const float* __restrict__ X) {
    const int idx = blockIdx.x * 256 + threadIdx.x;
    const float4 v = ((const float4*)X)[idx];
    const int m  = idx >> 8;
    const int k4 = (idx & 255) * 4;
    ushort a[4], b[4];
    split2s(v.x, a[0], b[0]);
    split2s(v.y, a[1], b[1]);
    split2s(v.z, a[2], b[2]);
    split2s(v.w, a[3], b[3]);
    ushort* row = g_xs + (size_t)m * 2048 + k4;
    int2 oa; oa.x = pack2(a[0], a[1]); oa.y = pack2(a[2], a[3]);
    int2 ob; ob.x = pack2(b[0], b[1]); ob.y = pack2(b[2], b[3]);
    *(int2*)(row)        = oa;
    *(int2*)(row + 1024) = ob;
}

// ---------------------------------------------------------------------------
// Wp [k][n] f32 -> g_WpT [n][2048] fp16: [k: a][1024+k: b] (transpose + split)
// ---------------------------------------------------------------------------
__global__ __launch_bounds__(256) void splitT_Wp(const float* __restrict__ Wp) {
    __shared__ float t[64][68];
    const int k0 = blockIdx.x * 64;
    const int n0 = blockIdx.y * 64;
    const int r = threadIdx.x >> 2;
    const int c = (threadIdx.x & 3) * 16;
    const float* src = Wp + (size_t)(k0 + r) * HN_ + n0 + c;
    #pragma unroll
    for (int q = 0; q < 4; ++q)
        *(float4*)&t[r][c + 4 * q] = ((const float4*)src)[q];
    __syncthreads();
    ushort ha[16], hb[16];
    #pragma unroll
    for (int j = 0; j < 16; ++j)
        split2s(t[c + j][r], ha[j], hb[j]);
    int4 a0, a1, b0, b1;
    a0.x = pack2(ha[0], ha[1]);   a0.y = pack2(ha[2], ha[3]);
    a0.z = pack2(ha[4], ha[5]);   a0.w = pack2(ha[6], ha[7]);
    a1.x = pack2(ha[8], ha[9]);   a1.y = pack2(ha[10], ha[11]);
    a1.z = pack2(ha[12], ha[13]); a1.w = pack2(ha[14], ha[15]);
    b0.x = pack2(hb[0], hb[1]);   b0.y = pack2(hb[2], hb[3]);
    b0.z = pack2(hb[4], hb[5]);   b0.w = pack2(hb[6], hb[7]);
    b1.x = pack2(hb[8], hb[9]);   b1.y = pack2(hb[10], hb[11]);
    b1.z = pack2(hb[12], hb[13]); b1.w = pack2(hb[14], hb[15]);
    ushort* dst = g_WpT + (size_t)(n0 + r) * 2048 + k0 + c;
    *(int4*)(dst)        = a0; *(int4*)(dst + 8)    = a1;
    *(int4*)(dst + 1024) = b0; *(int4*)(dst + 1032) = b1;
}

// ---------------------------------------------------------------------------
// Wo [hn][d] f32 -> g_WoT [d][hn] fp16 (transpose + cast)
// ---------------------------------------------------------------------------
__global__ __launch_bounds__(256) void castT_Wo(const float* __restrict__ Wo) {
    __shared__ float t[64][68];
    const int k0 = blockIdx.x * 64;   // hn
    const int n0 = blockIdx.y * 64;   // d
    const int r = threadIdx.x >> 2;
    const int c = (threadIdx.x & 3) * 16;
    const float* src = Wo + (size_t)(k0 + r) * D_ + n0 + c;
    #pragma unroll
    for (int q = 0; q < 4; ++q)
        *(float4*)&t[r][c + 4 * q] = ((const float4*)src)[q];
    __syncthreads();
    ushort h[16];
    #pragma unroll
    for (int j = 0; j < 16; ++j) h[j] = f2h(t[c + j][r]);
    ushort* dst = g_WoT + (size_t)(n0 + r) * 1024 + k0 + c;
    int4 o0, o1;
    o0.x = pack2(h[0], h[1]);   o0.y = pack2(h[2], h[3]);
    o0.z = pack2(h[4], h[5]);   o0.w = pack2(h[6], h[7]);
    o1.x = pack2(h[8], h[9]);   o1.y = pack2(h[10], h[11]);
    o1.z = pack2(h[12], h[13]); o1.w = pack2(h[14], h[15]);
    *(int4*)dst = o0;
    *(int4*)(dst + 8) = o1;
}

// ---------------------------------------------------------------------------
// MFMA main loop, BM=BN=128, BK=32, 4 waves (2M x 2N), 256 threads.
// Wave output 64x64 (acc 4x4). LDS: 2 x 16KB double buffer (A 8KB + B 8KB)
// = 32KB -> 4 blocks/CU = 16 waves/CU, 4 independent barrier groups.
// 2 raw s_barriers per K-tile, counted vmcnt(4). Swizzle for 64B rows:
// LDS slot s holds global k-slot s^(row&3) (applied on global source, LDS
// dest stays linear tid*16); read slot = h^(row&3). Verified 2-way (free).
// SPLIT maps (accumulation order identical to verified r3+ path):
//   t<32: a*aw ; 32..63: a*bw ; 64..95: b*aw.
// ---------------------------------------------------------------------------
template<int NT, int SPLIT>
__device__ __forceinline__ void gemm_mainloop(const ushort* __restrict__ A,
                                              const ushort* __restrict__ Bm,
                                              ushort* lds,
                                              int m0, int n0, int tid,
                                              f32x4 (&acc)[4][4]) {
    constexpr int KROW = SPLIT ? 2048 : 1024;      // stored row elems
    const int l   = tid & 63, wid = tid >> 6;
    const int wm  = wid >> 1, wn = wid & 1;
    const int l15 = l & 15, h = l >> 4;
    const int row4 = tid >> 2;                     // 0..63 (staging row)
    const int soff = ((tid & 3) ^ (row4 & 3)) << 4; // swizzled source slot
    const char* gA = (const char*)(A + (size_t)m0 * KROW);
    const char* gB = (const char*)(Bm + (size_t)n0 * KROW);
    const int rdA = (wm * 64 + l15) * 64 + ((h ^ (l15 & 3)) << 4);
    const int rdB = 8192 + (wn * 64 + l15) * 64 + ((h ^ (l15 & 3)) << 4);

    #define AOFF(T) ((SPLIT && (T) >= 64) ? 2048 + ((T) - 64) * 64 : ((T) & 31) * 64)
    #define BOFF(T) (SPLIT ? ((T) < 32 ? (T) * 64 : ((T) < 64 ? 2048 + ((T) - 32) * 64 \
                                                              : ((T) - 64) * 64)) : (T) * 64)

    #define STAGE(T, BUF) do {                                                    \
        const int ao_ = AOFF(T), bo_ = BOFF(T);                                   \
        char* lb_ = (char*)lds + (BUF) * 16384;                                   \
        gload16(gA + (size_t)(row4)      * (KROW * 2) + ao_ + soff, lb_ + tid * 16);          \
        gload16(gA + (size_t)(row4 + 64) * (KROW * 2) + ao_ + soff, lb_ + 4096 + tid * 16);   \
        gload16(gB + (size_t)(row4)      * (KROW * 2) + bo_ + soff, lb_ + 8192 + tid * 16);   \
        gload16(gB + (size_t)(row4 + 64) * (KROW * 2) + bo_ + soff, lb_ + 12288 + tid * 16);  \
    } while (0)

    #define SB __builtin_amdgcn_sched_barrier(0)

    STAGE(0, 0);

    #pragma unroll 2
    for (int t = 0; t < NT; ++t) {
        SB; __builtin_amdgcn_s_barrier(); SB;      // bar1: prior reads done
        if (t + 1 < NT) {
            STAGE(t + 1, (t + 1) & 1);
            asm volatile("s_waitcnt vmcnt(4)" ::: "memory");   // tile t landed
        } else {
            asm volatile("s_waitcnt vmcnt(0)" ::: "memory");
        }
        SB; __builtin_amdgcn_s_barrier(); SB;      // bar2: publish tile t

        const char* bb = (const char*)lds + (t & 1) * 16384;
        f16x8 Aa[4], Bb[4];
        #pragma unroll
        for (int i = 0; i < 4; ++i) Aa[i] = *(const f16x8*)(bb + rdA + i * 1024);
        #pragma unroll
        for (int j = 0; j < 4; ++j) Bb[j] = *(const f16x8*)(bb + rdB + j * 1024);
        __builtin_amdgcn_s_setprio(1);
        #pragma unroll
        for (int i = 0; i < 4; ++i)
            #pragma unroll
            for (int j = 0; j < 4; ++j)
                acc[i][j] = __builtin_amdgcn_mfma_f32_16x16x32_f16(
                    Aa[i], Bb[j], acc[i][j], 0, 0, 0);
        __builtin_amdgcn_s_setprio(0);
    }
    #undef STAGE
    #undef SB
    #undef AOFF
    #undef BOFF
}

// 512 blocks: per XCD 8 M-panels x 8 N-panels (A fetched once chip-wide)
__device__ __forceinline__ void tile_map(int bid, int& m0, int& n0) {
    const int xcd = bid & 7;
    const int idx = bid >> 3;              // 0..63
    m0 = (xcd * 8 + (idx >> 3)) * 128;     // 64 M-tiles
    n0 = (idx & 7) * 128;                  // 8 N-tiles
}

// GEMM1: g_xs x g_WpT -> pi*tanh(acc*2^-24 + bias) -> g_ph[b][n][s]
__global__ __launch_bounds__(256, 4) void gemm1(const float* __restrict__ bias) {
    __shared__ ushort lds[2 * 8192];   // 32 KB
    const int tid = threadIdx.x;
    int m0, n0;
    tile_map(blockIdx.x, m0, n0);
    const int wid = tid >> 6, l = tid & 63;
    const int wm = wid >> 1, wn = wid & 1;

    f32x4 acc[4][4];
    #pragma unroll
    for (int i = 0; i < 4; ++i)
        #pragma unroll
        for (int j = 0; j < 4; ++j) acc[i][j] = (f32x4){0.f, 0.f, 0.f, 0.f};

    gemm_mainloop<96, 1>(g_xs, g_WpT, lds, m0, n0, tid, acc);

    const int r4 = (l >> 4) * 4;
    const int cn = l & 15;
    #pragma unroll
    for (int i = 0; i < 4; ++i) {
        const int mg = m0 + wm * 64 + i * 16 + r4;
        const int bidx = mg >> 11;
        const int sg = mg & 2047;
        #pragma unroll
        for (int jj = 0; jj < 4; ++jj) {
            const int ng = n0 + wn * 64 + jj * 16 + cn;
            const float bb = bias[ng];
            float4 o;
            o.x = PI_ * tanhf(fmaf(acc[i][jj][0], INVSC2_, bb));
            o.y = PI_ * tanhf(fmaf(acc[i][jj][1], INVSC2_, bb));
            o.z = PI_ * tanhf(fmaf(acc[i][jj][2], INVSC2_, bb));
            o.w = PI_ * tanhf(fmaf(acc[i][jj][3], INVSC2_, bb));
            *(float4*)(g_ph + ((size_t)bidx * HN_ + ng) * S_ + sg) = o;
        }
    }
}

// GEMM3: g_phT x g_WoT + bias -> Y [8192][1024] f32
__global__ __launch_bounds__(256, 4) void gemm3(const float* __restrict__ bias,
                                                float* __restrict__ Y) {
    __shared__ ushort lds[2 * 8192];   // 32 KB
    const int tid = threadIdx.x;
    int m0, n0;
    tile_map(blockIdx.x, m0, n0);
    const int wid = tid >> 6, l = tid & 63;
    const int wm = wid >> 1, wn = wid & 1;

    f32x4 acc[4][4];
    #pragma unroll
    for (int i = 0; i < 4; ++i)
        #pragma unroll
        for (int j = 0; j < 4; ++j) acc[i][j] = (f32x4){0.f, 0.f, 0.f, 0.f};

    gemm_mainloop<32, 0>(g_phT, g_WoT, lds, m0, n0, tid, acc);

    const int r4 = (l >> 4) * 4;
    const int cn = l & 15;
    #pragma unroll
    for (int i = 0; i < 4; ++i) {
        const int mg = m0 + wm * 64 + i * 16 + r4;
        #pragma unroll
        for (int jj = 0; jj < 4; ++jj) {
            const int ng = n0 + wn * 64 + jj * 16 + cn;
            const float bb = bias[ng];
            #pragma unroll
            for (int r = 0; r < 4; ++r)
                Y[(size_t)(mg + r) * D_ + ng] = acc[i][jj][r] + bb;
        }
    }
}

// ---------------------------------------------------------------------------
// Kuramoto (unchanged, verified): one wave per (b, hn), 10 iters in registers.
// ---------------------------------------------------------------------------
__global__ __launch_bounds__(256) void kuramoto(const int* __restrict__ mask,
                                                const float* __restrict__ natf,
                                                const float* __restrict__ coup) {
    const int wave = blockIdx.x * 4 + (threadIdx.x >> 6);
    const int lane = threadIdx.x & 63;
    const int b = wave >> 10;
    const int hn = wave & 1023;
    const int h = hn >> 7;

    const float wf = natf[hn];
    const float K = coup[h];

    const float* base = g_ph + ((size_t)b * HN_ + hn) * S_;

    float ph[32];
    #pragma unroll
    for (int i = 0; i < 8; ++i) {
        float4 v = *(const float4*)(base + i * 256 + lane * 4);
        ph[4 * i + 0] = v.x; ph[4 * i + 1] = v.y;
        ph[4 * i + 2] = v.z; ph[4 * i + 3] = v.w;
    }

    const int* mb = mask + b * S_;
    unsigned mbits = 0;
    #pragma unroll
    for (int i = 0; i < 8; ++i) {
        int4 mv = *(const int4*)(mb + i * 256 + lane * 4);
        mbits |= (mv.x != 0 ? 1u : 0u) << (4 * i + 0);
        mbits |= (mv.y != 0 ? 1u : 0u) << (4 * i + 1);
        mbits |= (mv.z != 0 ? 1u : 0u) << (4 * i + 2);
        mbits |= (mv.w != 0 ? 1u : 0u) << (4 * i + 3);
    }

    for (int it = 0; it < ITERS_; ++it) {
        float s[32], c[32];
        float ls = 0.f, lc = 0.f;
        #pragma unroll
        for (int i = 0; i < 32; ++i) {
            s[i] = __sinf(ph[i]);
            c[i] = __cosf(ph[i]);
            const float mf = (float)((mbits >> i) & 1u);
            ls = fmaf(mf, s[i], ls);
            lc = fmaf(mf, c[i], lc);
        }
        #pragma unroll
        for (int off = 32; off; off >>= 1) {
            ls += __shfl_xor(ls, off);
            lc += __shfl_xor(lc, off);
        }
        const float ms = ls * (1.f / 2048.f);
        const float mc = lc * (1.f / 2048.f);
        #pragma unroll
        for (int i = 0; i < 32; ++i) {
            const float dth = fmaf(K, fmaf(s[i], mc, -c[i] * ms), wf);
            float t = fmaf(DT_, dth, ph[i]) + PI_;
            t -= TWOPI_ * floorf(t * INV2PI_);
            ph[i] = t - PI_;
        }
    }

    ushort* ob = g_phh + ((size_t)b * HN_ + hn) * S_;
    #pragma unroll
    for (int i = 0; i < 8; ++i) {
        ushort4 o;
        o.x = f2h(ph[4 * i + 0]); o.y = f2h(ph[4 * i + 1]);
        o.z = f2h(ph[4 * i + 2]); o.w = f2h(ph[4 * i + 3]);
        *(ushort4*)(ob + i * 256 + lane * 4) = o;
    }
}

// ---------------------------------------------------------------------------
// g_phh [b][hn][s] fp16 -> g_phT [(b,s)][hn] fp16  (64x64 tiles, unchanged)
// ---------------------------------------------------------------------------
__global__ __launch_bounds__(256) void transpose_ph() {
    __shared__ ushort t[64][72];
    const int b = blockIdx.z;
    const int h0 = blockIdx.y * 64;
    const int s0 = blockIdx.x * 64;
    const int r = threadIdx.x >> 2;
    const int c = (threadIdx.x & 3) * 16;
    const ushort* src = g_phh + ((size_t)b * HN_ + h0 + r) * S_ + s0 + c;
    *(int4*)&t[r][c] = *(const int4*)src;
    *(int4*)&t[r][c + 8] = *(const int4*)(src + 8);
    __syncthreads();
    ushort o[16];
    #pragma unroll
    for (int j = 0; j < 16; ++j) o[j] = t[c + j][r];
    ushort* dst = g_phT + ((size_t)(b * S_ + s0 + r)) * HN_ + h0 + c;
    int4 o0, o1;
    o0.x = pack2(o[0], o[1]);   o0.y = pack2(o[2], o[3]);
    o0.z = pack2(o[4], o[5]);   o0.w = pack2(o[6], o[7]);
    o1.x = pack2(o[8], o[9]);   o1.y = pack2(o[10], o[11]);
    o1.z = pack2(o[12], o[13]); o1.w = pack2(o[14], o[15]);
    *(int4*)dst = o0;
    *(int4*)(dst + 8) = o1;
}

extern "C" void kernel_launch(void* const* d_in, const int* in_sizes, int n_in,
                              void* d_out, int out_size, void* d_ws, size_t ws_size,
                              hipStream_t stream) {
    const float* x    = (const float*)d_in[0];
    const int*   mask = (const int*)d_in[1];
    const float* Wp   = (const float*)d_in[2];
    const float* bp   = (const float*)d_in[3];
    const float* natf = (const float*)d_in[4];
    const float* coup = (const float*)d_in[5];
    const float* Wo   = (const float*)d_in[6];
    const float* bo   = (const float*)d_in[7];
    float* y = (float*)d_out;

    split_x  <<<dim3(8192),         256, 0, stream>>>(x);
    splitT_Wp<<<dim3(16, 16),       256, 0, stream>>>(Wp);
    castT_Wo <<<dim3(16, 16),       256, 0, stream>>>(Wo);
    gemm1    <<<dim3(512),          256, 0, stream>>>(bp);
    kuramoto <<<dim3(1024),         256, 0, stream>>>(mask, natf, coup);
    transpose_ph<<<dim3(32, 16, 4), 256, 0, stream>>>();
    gemm3    <<<dim3(512),          256, 0, stream>>>(bo, y);
}

// Round 11
// 189.152 us; speedup vs baseline: 1.0181x; 1.0181x over previous
//
#include <hip/hip_runtime.h>
#include <math.h>

#define S_ 2048
#define D_ 1024
#define HN_ 1024
#define B_ 4
#define M_ 8192
#define ITERS_ 10
#define DT_ 0.1f
#define PI_ 3.14159265358979323846f
#define TWOPI_ 6.28318530717958647692f
#define INV2PI_ 0.15915494309189533577f
#define SCALE_ 4096.0f
#define INVSC2_ (1.0f / 16777216.0f)   // 2^-24

typedef __attribute__((ext_vector_type(8))) _Float16 f16x8;
typedef __attribute__((ext_vector_type(4))) float f32x4;

// static scratch
__device__ __align__(16) ushort g_xs [(size_t)M_ * 2048];   // x split [a|b] fp16, scaled 4096
__device__ __align__(16) ushort g_WpT[(size_t)HN_ * 2048];  // Wp^T split [a|b] fp16, scaled
__device__ __align__(16) ushort g_WoT[(size_t)D_ * 1024];   // Wo^T fp16 [d][hn]
__device__ __align__(16) float  g_ph [(size_t)B_ * HN_ * S_]; // phases f32 [b][hn][s]
__device__ __align__(16) ushort g_phh[(size_t)B_ * HN_ * S_]; // final phases fp16
__device__ __align__(16) ushort g_phT[(size_t)M_ * HN_];      // phases fp16 [(b,s)][hn]

__device__ __forceinline__ ushort f2h(float f) {
    union { _Float16 h; ushort u; } v; v.h = (_Float16)f; return v.u;
}
__device__ __forceinline__ void split2s(float x, ushort& A, ushort& Bc) {
    const float xs = x * SCALE_;
    union { _Float16 h; ushort u; } va, vb;
    va.h = (_Float16)xs;
    const float r = xs - (float)va.h;   // exact
    vb.h = (_Float16)r;
    A = va.u; Bc = vb.u;
}
__device__ __forceinline__ void gload16(const void* g, void* l) {
    __builtin_amdgcn_global_load_lds(
        (const __attribute__((address_space(1))) void*)g,
        (__attribute__((address_space(3))) void*)l, 16, 0, 0);
}
__device__ __forceinline__ int pack2(ushort a, ushort b) {
    return (int)(unsigned)a | ((int)(unsigned)b << 16);
}

// ---------------------------------------------------------------------------
// x [8192][1024] f32 -> g_xs [8192][2048] fp16: [k: a][1024+k: b]
// ---------------------------------------------------------------------------
__global__ __launch_bounds__(256) void split_x(const float* __restrict__ X) {
    const int idx = blockIdx.x * 256 + threadIdx.x;
    const float4 v = ((const float4*)X)[idx];
    const int m  = idx >> 8;
    const int k4 = (idx & 255) * 4;
    ushort a[4], b[4];
    split2s(v.x, a[0], b[0]);
    split2s(v.y, a[1], b[1]);
    split2s(v.z, a[2], b[2]);
    split2s(v.w, a[3], b[3]);
    ushort* row = g_xs + (size_t)m * 2048 + k4;
    int2 oa; oa.x = pack2(a[0], a[1]); oa.y = pack2(a[2], a[3]);
    int2 ob; ob.x = pack2(b[0], b[1]); ob.y = pack2(b[2], b[3]);
    *(int2*)(row)        = oa;
    *(int2*)(row + 1024) = ob;
}

// ---------------------------------------------------------------------------
// Wp [k][n] f32 -> g_WpT [n][2048] fp16: [k: a][1024+k: b] (transpose + split)
// ---------------------------------------------------------------------------
__global__ __launch_bounds__(256) void splitT_Wp(const float* __restrict__ Wp) {
    __shared__ float t[64][68];
    const int k0 = blockIdx.x * 64;
    const int n0 = blockIdx.y * 64;
    const int r = threadIdx.x >> 2;
    const int c = (threadIdx.x & 3) * 16;
    const float* src = Wp + (size_t)(k0 + r) * HN_ + n0 + c;
    #pragma unroll
    for (int q = 0; q < 4; ++q)
        *(float4*)&t[r][c + 4 * q] = ((const float4*)src)[q];
    __syncthreads();
    ushort ha[16], hb[16];
    #pragma unroll
    for (int j = 0; j < 16; ++j)
        split2s(t[c + j][r], ha[j], hb[j]);
    int4 a0, a1, b0, b1;
    a0.x = pack2(ha[0], ha[1]);   a0.y = pack2(ha[2], ha[3]);
    a0.z = pack2(ha[4], ha[5]);   a0.w = pack2(ha[6], ha[7]);
    a1.x = pack2(ha[8], ha[9]);   a1.y = pack2(ha[10], ha[11]);
    a1.z = pack2(ha[12], ha[13]); a1.w = pack2(ha[14], ha[15]);
    b0.x = pack2(hb[0], hb[1]);   b0.y = pack2(hb[2], hb[3]);
    b0.z = pack2(hb[4], hb[5]);   b0.w = pack2(hb[6], hb[7]);
    b1.x = pack2(hb[8], hb[9]);   b1.y = pack2(hb[10], hb[11]);
    b1.z = pack2(hb[12], hb[13]); b1.w = pack2(hb[14], hb[15]);
    ushort* dst = g_WpT + (size_t)(n0 + r) * 2048 + k0 + c;
    *(int4*)(dst)        = a0; *(int4*)(dst + 8)    = a1;
    *(int4*)(dst + 1024) = b0; *(int4*)(dst + 1032) = b1;
}

// ---------------------------------------------------------------------------
// Wo [hn][d] f32 -> g_WoT [d][hn] fp16 (transpose + cast)
// ---------------------------------------------------------------------------
__global__ __launch_bounds__(256) void castT_Wo(const float* __restrict__ Wo) {
    __shared__ float t[64][68];
    const int k0 = blockIdx.x * 64;   // hn
    const int n0 = blockIdx.y * 64;   // d
    const int r = threadIdx.x >> 2;
    const int c = (threadIdx.x & 3) * 16;
    const float* src = Wo + (size_t)(k0 + r) * D_ + n0 + c;
    #pragma unroll
    for (int q = 0; q < 4; ++q)
        *(float4*)&t[r][c + 4 * q] = ((const float4*)src)[q];
    __syncthreads();
    ushort h[16];
    #pragma unroll
    for (int j = 0; j < 16; ++j) h[j] = f2h(t[c + j][r]);
    ushort* dst = g_WoT + (size_t)(n0 + r) * 1024 + k0 + c;
    int4 o0, o1;
    o0.x = pack2(h[0], h[1]);   o0.y = pack2(h[2], h[3]);
    o0.z = pack2(h[4], h[5]);   o0.w = pack2(h[6], h[7]);
    o1.x = pack2(h[8], h[9]);   o1.y = pack2(h[10], h[11]);
    o1.z = pack2(h[12], h[13]); o1.w = pack2(h[14], h[15]);
    *(int4*)dst = o0;
    *(int4*)(dst + 8) = o1;
}

// ---------------------------------------------------------------------------
// MFMA main loop, BM=128 x BN=64, BK=64, 8 waves (4M x 2N), 512 threads.
// Wave output 32x32 (acc 2x2). LDS: 2 x 24KB (A 16KB + B 8KB) = 48KB ->
// 3 blocks/CU = 24 waves/CU = 6 waves/SIMD (the round-11 lever).
// r8's proven skeleton: 2 raw s_barriers/K-tile, counted vmcnt(3),
// 128B-row T2 swizzle both-sides (conflicts 0 in r8/r9).
// K-dedup [a|b] storage; per-tile source maps (product order a*aw, a*bw,
// b*aw — identical accumulation order to the verified r3+ path).
// Race audit: each wave's ds_reads are lgkm-drained before its MFMAs, which
// precede its bar1 arrival; STAGE(t+1) (overwrites buf read at t-1) issues
// after bar1; ds_reads of buf[t] follow bar2 which follows all waves'
// vmcnt(3) (tile-t loads complete, in-order per wave).
// ---------------------------------------------------------------------------
template<int NT, int SPLIT>
__device__ __forceinline__ void gemm_mainloop(const ushort* __restrict__ A,
                                              const ushort* __restrict__ Bm,
                                              ushort* lds,
                                              int m0, int n0, int tid,
                                              f32x4 (&acc)[2][2]) {
    constexpr int KROW = SPLIT ? 2048 : 1024;      // stored row elems
    const int l = tid & 63, wid = tid >> 6;
    const int wm = wid >> 1, wn = wid & 1;
    const int r8   = l >> 3;                       // 0..7
    const int swzo = ((l & 7) * 16) ^ (r8 << 4);   // inverse-swizzled source byte
    const char* gA = (const char*)(A + (size_t)m0 * KROW);
    const char* gB = (const char*)(Bm + (size_t)n0 * KROW);

    const int l15 = l & 15;
    const int xk  = (l15 & 7) << 4;
    const int sl0 = (((l >> 4) * 16)) ^ xk;        // ks=0 slot (bytes 0..63)
    const int sl1 = (64 + ((l >> 4) * 16)) ^ xk;   // ks=1 slot (bytes 64..127)
    const char* pA = (const char*)lds + (wm * 32 + l15) * 128;
    const char* pB = (const char*)lds + 16384 + (wn * 32 + l15) * 128;

    // byte offsets of K-tile T within the stored [a|b] row (b starts at 2048B)
    #define AOFF(T) ((size_t)(SPLIT ? ((T) < 32 ? ((T) & 15) * 128 : 2048 + ((T) - 32) * 128) \
                                    : (T) * 128))
    #define BOFF(T) ((size_t)(SPLIT ? ((T) < 16 ? (T) * 128                                   \
                                     : ((T) < 32 ? 2048 + ((T) - 16) * 128                    \
                                                 : ((T) - 32) * 128))                         \
                                    : (T) * 128))

    #define STAGE(T, BUF) do {                                                     \
        const size_t ao_ = AOFF(T) + swzo, bo_ = BOFF(T) + swzo;                   \
        char* lb_ = (char*)lds + (BUF) * 24576;                                    \
        gload16(gA + (size_t)(wid * 16 + r8)     * (KROW * 2) + ao_,               \
                lb_ + wid * 2048);                                                 \
        gload16(gA + (size_t)(wid * 16 + 8 + r8) * (KROW * 2) + ao_,               \
                lb_ + wid * 2048 + 1024);                                          \
        gload16(gB + (size_t)(wid * 8 + r8)      * (KROW * 2) + bo_,               \
                lb_ + 16384 + wid * 1024);                                         \
    } while (0)

    #define SB __builtin_amdgcn_sched_barrier(0)

    STAGE(0, 0);

    #pragma unroll 2
    for (int t = 0; t < NT; ++t) {
        SB; __builtin_amdgcn_s_barrier(); SB;      // bar1: prior reads done
        if (t + 1 < NT) {
            STAGE(t + 1, (t + 1) & 1);
            asm volatile("s_waitcnt vmcnt(3)" ::: "memory");   // tile t landed
        } else {
            asm volatile("s_waitcnt vmcnt(0)" ::: "memory");
        }
        SB; __builtin_amdgcn_s_barrier(); SB;      // bar2: publish tile t

        const int bo = (t & 1) * 24576;
        f16x8 Aa[2][2], Bb[2][2];
        #pragma unroll
        for (int i = 0; i < 2; ++i) {
            Aa[i][0] = *(const f16x8*)(pA + bo + i * 2048 + sl0);
            Aa[i][1] = *(const f16x8*)(pA + bo + i * 2048 + sl1);
        }
        #pragma unroll
        for (int j = 0; j < 2; ++j) {
            Bb[j][0] = *(const f16x8*)(pB + bo + j * 2048 + sl0);
            Bb[j][1] = *(const f16x8*)(pB + bo + j * 2048 + sl1);
        }
        __builtin_amdgcn_s_setprio(1);
        #pragma unroll
        for (int ks = 0; ks < 2; ++ks)
            #pragma unroll
            for (int i = 0; i < 2; ++i)
                #pragma unroll
                for (int j = 0; j < 2; ++j)
                    acc[i][j] = __builtin_amdgcn_mfma_f32_16x16x32_f16(
                        Aa[i][ks], Bb[j][ks], acc[i][j], 0, 0, 0);
        __builtin_amdgcn_s_setprio(0);
    }
    #undef STAGE
    #undef SB
    #undef AOFF
    #undef BOFF
}

// 1024 blocks: per XCD 8 M-panels x 16 N-panels (A fetched once chip-wide)
__device__ __forceinline__ void tile_map(int bid, int& m0, int& n0) {
    const int xcd = bid & 7;
    const int idx = bid >> 3;              // 0..127
    m0 = (xcd * 8 + (idx >> 4)) * 128;     // 64 M-tiles
    n0 = (idx & 15) * 64;                  // 16 N-tiles
}

// GEMM1: g_xs x g_WpT -> pi*tanh(acc*2^-24 + bias) -> g_ph[b][n][s]
__global__ __launch_bounds__(512, 6) void gemm1(const float* __restrict__ bias) {
    __shared__ ushort lds[2 * 12288];   // 48 KB
    const int tid = threadIdx.x;
    int m0, n0;
    tile_map(blockIdx.x, m0, n0);
    const int wid = tid >> 6, l = tid & 63;
    const int wm = wid >> 1, wn = wid & 1;

    f32x4 acc[2][2];
    #pragma unroll
    for (int i = 0; i < 2; ++i)
        #pragma unroll
        for (int j = 0; j < 2; ++j) acc[i][j] = (f32x4){0.f, 0.f, 0.f, 0.f};

    gemm_mainloop<48, 1>(g_xs, g_WpT, lds, m0, n0, tid, acc);

    const int r4 = (l >> 4) * 4;
    const int cn = l & 15;
    #pragma unroll
    for (int i = 0; i < 2; ++i) {
        const int mg = m0 + wm * 32 + i * 16 + r4;
        const int bidx = mg >> 11;
        const int sg = mg & 2047;
        #pragma unroll
        for (int jj = 0; jj < 2; ++jj) {
            const int ng = n0 + wn * 32 + jj * 16 + cn;
            const float bb = bias[ng];
            float4 o;
            o.x = PI_ * tanhf(fmaf(acc[i][jj][0], INVSC2_, bb));
            o.y = PI_ * tanhf(fmaf(acc[i][jj][1], INVSC2_, bb));
            o.z = PI_ * tanhf(fmaf(acc[i][jj][2], INVSC2_, bb));
            o.w = PI_ * tanhf(fmaf(acc[i][jj][3], INVSC2_, bb));
            *(float4*)(g_ph + ((size_t)bidx * HN_ + ng) * S_ + sg) = o;
        }
    }
}

// GEMM3: g_phT x g_WoT + bias -> Y [8192][1024] f32
__global__ __launch_bounds__(512, 6) void gemm3(const float* __restrict__ bias,
                                                float* __restrict__ Y) {
    __shared__ ushort lds[2 * 12288];   // 48 KB
    const int tid = threadIdx.x;
    int m0, n0;
    tile_map(blockIdx.x, m0, n0);
    const int wid = tid >> 6, l = tid & 63;
    const int wm = wid >> 1, wn = wid & 1;

    f32x4 acc[2][2];
    #pragma unroll
    for (int i = 0; i < 2; ++i)
        #pragma unroll
        for (int j = 0; j < 2; ++j) acc[i][j] = (f32x4){0.f, 0.f, 0.f, 0.f};

    gemm_mainloop<16, 0>(g_phT, g_WoT, lds, m0, n0, tid, acc);

    const int r4 = (l >> 4) * 4;
    const int cn = l & 15;
    #pragma unroll
    for (int i = 0; i < 2; ++i) {
        const int mg = m0 + wm * 32 + i * 16 + r4;
        #pragma unroll
        for (int jj = 0; jj < 2; ++jj) {
            const int ng = n0 + wn * 32 + jj * 16 + cn;
            const float bb = bias[ng];
            #pragma unroll
            for (int r = 0; r < 4; ++r)
                Y[(size_t)(mg + r) * D_ + ng] = acc[i][jj][r] + bb;
        }
    }
}

// ---------------------------------------------------------------------------
// Kuramoto (unchanged, verified): one wave per (b, hn), 10 iters in registers.
// ---------------------------------------------------------------------------
__global__ __launch_bounds__(256) void kuramoto(const int* __restrict__ mask,
                                                const float* __restrict__ natf,
                                                const float* __restrict__ coup) {
    const int wave = blockIdx.x * 4 + (threadIdx.x >> 6);
    const int lane = threadIdx.x & 63;
    const int b = wave >> 10;
    const int hn = wave & 1023;
    const int h = hn >> 7;

    const float wf = natf[hn];
    const float K = coup[h];

    const float* base = g_ph + ((size_t)b * HN_ + hn) * S_;

    float ph[32];
    #pragma unroll
    for (int i = 0; i < 8; ++i) {
        float4 v = *(const float4*)(base + i * 256 + lane * 4);
        ph[4 * i + 0] = v.x; ph[4 * i + 1] = v.y;
        ph[4 * i + 2] = v.z; ph[4 * i + 3] = v.w;
    }

    const int* mb = mask + b * S_;
    unsigned mbits = 0;
    #pragma unroll
    for (int i = 0; i < 8; ++i) {
        int4 mv = *(const int4*)(mb + i * 256 + lane * 4);
        mbits |= (mv.x != 0 ? 1u : 0u) << (4 * i + 0);
        mbits |= (mv.y != 0 ? 1u : 0u) << (4 * i + 1);
        mbits |= (mv.z != 0 ? 1u : 0u) << (4 * i + 2);
        mbits |= (mv.w != 0 ? 1u : 0u) << (4 * i + 3);
    }

    for (int it = 0; it < ITERS_; ++it) {
        float s[32], c[32];
        float ls = 0.f, lc = 0.f;
        #pragma unroll
        for (int i = 0; i < 32; ++i) {
            s[i] = __sinf(ph[i]);
            c[i] = __cosf(ph[i]);
            const float mf = (float)((mbits >> i) & 1u);
            ls = fmaf(mf, s[i], ls);
            lc = fmaf(mf, c[i], lc);
        }
        #pragma unroll
        for (int off = 32; off; off >>= 1) {
            ls += __shfl_xor(ls, off);
            lc += __shfl_xor(lc, off);
        }
        const float ms = ls * (1.f / 2048.f);
        const float mc = lc * (1.f / 2048.f);
        #pragma unroll
        for (int i = 0; i < 32; ++i) {
            const float dth = fmaf(K, fmaf(s[i], mc, -c[i] * ms), wf);
            float t = fmaf(DT_, dth, ph[i]) + PI_;
            t -= TWOPI_ * floorf(t * INV2PI_);
            ph[i] = t - PI_;
        }
    }

    ushort* ob = g_phh + ((size_t)b * HN_ + hn) * S_;
    #pragma unroll
    for (int i = 0; i < 8; ++i) {
        ushort4 o;
        o.x = f2h(ph[4 * i + 0]); o.y = f2h(ph[4 * i + 1]);
        o.z = f2h(ph[4 * i + 2]); o.w = f2h(ph[4 * i + 3]);
        *(ushort4*)(ob + i * 256 + lane * 4) = o;
    }
}

// ---------------------------------------------------------------------------
// g_phh [b][hn][s] fp16 -> g_phT [(b,s)][hn] fp16  (64x64 tiles, unchanged)
// ---------------------------------------------------------------------------
__global__ __launch_bounds__(256) void transpose_ph() {
    __shared__ ushort t[64][72];
    const int b = blockIdx.z;
    const int h0 = blockIdx.y * 64;
    const int s0 = blockIdx.x * 64;
    const int r = threadIdx.x >> 2;
    const int c = (threadIdx.x & 3) * 16;
    const ushort* src = g_phh + ((size_t)b * HN_ + h0 + r) * S_ + s0 + c;
    *(int4*)&t[r][c] = *(const int4*)src;
    *(int4*)&t[r][c + 8] = *(const int4*)(src + 8);
    __syncthreads();
    ushort o[16];
    #pragma unroll
    for (int j = 0; j < 16; ++j) o[j] = t[c + j][r];
    ushort* dst = g_phT + ((size_t)(b * S_ + s0 + r)) * HN_ + h0 + c;
    int4 o0, o1;
    o0.x = pack2(o[0], o[1]);   o0.y = pack2(o[2], o[3]);
    o0.z = pack2(o[4], o[5]);   o0.w = pack2(o[6], o[7]);
    o1.x = pack2(o[8], o[9]);   o1.y = pack2(o[10], o[11]);
    o1.z = pack2(o[12], o[13]); o1.w = pack2(o[14], o[15]);
    *(int4*)dst = o0;
    *(int4*)(dst + 8) = o1;
}

extern "C" void kernel_launch(void* const* d_in, const int* in_sizes, int n_in,
                              void* d_out, int out_size, void* d_ws, size_t ws_size,
                              hipStream_t stream) {
    const float* x    = (const float*)d_in[0];
    const int*   mask = (const int*)d_in[1];
    const float* Wp   = (const float*)d_in[2];
    const float* bp   = (const float*)d_in[3];
    const float* natf = (const float*)d_in[4];
    const float* coup = (const float*)d_in[5];
    const float* Wo   = (const float*)d_in[6];
    const float* bo   = (const float*)d_in[7];
    float* y = (float*)d_out;

    split_x  <<<dim3(8192),         256, 0, stream>>>(x);
    splitT_Wp<<<dim3(16, 16),       256, 0, stream>>>(Wp);
    castT_Wo <<<dim3(16, 16),       256, 0, stream>>>(Wo);
    gemm1    <<<dim3(1024),         512, 0, stream>>>(bp);
    kuramoto <<<dim3(1024),         256, 0, stream>>>(mask, natf, coup);
    transpose_ph<<<dim3(32, 16, 4), 256, 0, stream>>>();
    gemm3    <<<dim3(1024),         512, 0, stream>>>(bo, y);
}

// Round 12
// 188.181 us; speedup vs baseline: 1.0233x; 1.0052x over previous
//
#include <hip/hip_runtime.h>
#include <math.h>

#define S_ 2048
#define D_ 1024
#define HN_ 1024
#define B_ 4
#define M_ 8192
#define ITERS_ 10
#define DT_ 0.1f
#define PI_ 3.14159265358979323846f
#define TWOPI_ 6.28318530717958647692f
#define INV2PI_ 0.15915494309189533577f
#define SCALE_ 4096.0f
#define INVSC2_ (1.0f / 16777216.0f)   // 2^-24

typedef __attribute__((ext_vector_type(8))) _Float16 f16x8;
typedef __attribute__((ext_vector_type(4))) float f32x4;

// static scratch
__device__ __align__(16) ushort g_xs [(size_t)M_ * 2048];   // x split [a|b] fp16, scaled 4096
__device__ __align__(16) ushort g_WpT[(size_t)HN_ * 2048];  // Wp^T split [a|b] fp16, scaled
__device__ __align__(16) ushort g_WoT[(size_t)D_ * 1024];   // Wo^T fp16 [d][hn]
__device__ __align__(16) float  g_p0 [(size_t)B_ * HN_ * S_]; // gemm1 partial, K-half 0
__device__ __align__(16) float  g_p1 [(size_t)B_ * HN_ * S_]; // gemm1 partial, K-half 1
__device__ __align__(16) ushort g_phh[(size_t)B_ * HN_ * S_]; // final phases fp16 [b][hn][s]
__device__ __align__(16) ushort g_phT[(size_t)M_ * HN_];      // phases fp16 [(b,s)][hn]

__device__ __forceinline__ ushort f2h(float f) {
    union { _Float16 h; ushort u; } v; v.h = (_Float16)f; return v.u;
}
__device__ __forceinline__ void split2s(float x, ushort& A, ushort& Bc) {
    const float xs = x * SCALE_;
    union { _Float16 h; ushort u; } va, vb;
    va.h = (_Float16)xs;
    const float r = xs - (float)va.h;   // exact
    vb.h = (_Float16)r;
    A = va.u; Bc = vb.u;
}
__device__ __forceinline__ void gload16(const void* g, void* l) {
    __builtin_amdgcn_global_load_lds(
        (const __attribute__((address_space(1))) void*)g,
        (__attribute__((address_space(3))) void*)l, 16, 0, 0);
}
__device__ __forceinline__ int pack2(ushort a, ushort b) {
    return (int)(unsigned)a | ((int)(unsigned)b << 16);
}

// ---------------------------------------------------------------------------
// Merged prep: blocks [0,2048) = split_x (4 float4/thread);
//   [2048,2304) = Wp transpose+split ; [2304,2560) = Wo transpose+cast.
// Bodies identical to the individually-verified r11 kernels.
// ---------------------------------------------------------------------------
__global__ __launch_bounds__(256) void prep(const float* __restrict__ X,
                                            const float* __restrict__ Wp,
                                            const float* __restrict__ Wo) {
    __shared__ float t[64][68];
    const int bid = blockIdx.x;
    const int tid = threadIdx.x;
    if (bid < 2048) {
        #pragma unroll
        for (int p = 0; p < 4; ++p) {
            const int idx = bid * 1024 + p * 256 + tid;
            const float4 v = ((const float4*)X)[idx];
            const int m  = idx >> 8;
            const int k4 = (idx & 255) * 4;
            ushort a[4], b[4];
            split2s(v.x, a[0], b[0]);
            split2s(v.y, a[1], b[1]);
            split2s(v.z, a[2], b[2]);
            split2s(v.w, a[3], b[3]);
            ushort* row = g_xs + (size_t)m * 2048 + k4;
            int2 oa; oa.x = pack2(a[0], a[1]); oa.y = pack2(a[2], a[3]);
            int2 ob; ob.x = pack2(b[0], b[1]); ob.y = pack2(b[2], b[3]);
            *(int2*)(row)        = oa;
            *(int2*)(row + 1024) = ob;
        }
        return;
    }
    const int wb   = bid - 2048;
    const bool isWp = (wb < 256);
    const int g  = isWp ? wb : wb - 256;
    const int k0 = (g >> 4) * 64;
    const int n0 = (g & 15) * 64;
    const int r = tid >> 2;
    const int c = (tid & 3) * 16;
    const float* src = (isWp ? Wp : Wo) + (size_t)(k0 + r) * 1024 + n0 + c;
    #pragma unroll
    for (int q = 0; q < 4; ++q)
        *(float4*)&t[r][c + 4 * q] = ((const float4*)src)[q];
    __syncthreads();
    if (isWp) {
        ushort ha[16], hb[16];
        #pragma unroll
        for (int j = 0; j < 16; ++j)
            split2s(t[c + j][r], ha[j], hb[j]);
        int4 a0, a1, b0, b1;
        a0.x = pack2(ha[0], ha[1]);   a0.y = pack2(ha[2], ha[3]);
        a0.z = pack2(ha[4], ha[5]);   a0.w = pack2(ha[6], ha[7]);
        a1.x = pack2(ha[8], ha[9]);   a1.y = pack2(ha[10], ha[11]);
        a1.z = pack2(ha[12], ha[13]); a1.w = pack2(ha[14], ha[15]);
        b0.x = pack2(hb[0], hb[1]);   b0.y = pack2(hb[2], hb[3]);
        b0.z = pack2(hb[4], hb[5]);   b0.w = pack2(hb[6], hb[7]);
        b1.x = pack2(hb[8], hb[9]);   b1.y = pack2(hb[10], hb[11]);
        b1.z = pack2(hb[12], hb[13]); b1.w = pack2(hb[14], hb[15]);
        ushort* dst = g_WpT + (size_t)(n0 + r) * 2048 + k0 + c;
        *(int4*)(dst)        = a0; *(int4*)(dst + 8)    = a1;
        *(int4*)(dst + 1024) = b0; *(int4*)(dst + 1032) = b1;
    } else {
        ushort h[16];
        #pragma unroll
        for (int j = 0; j < 16; ++j) h[j] = f2h(t[c + j][r]);
        ushort* dst = g_WoT + (size_t)(n0 + r) * 1024 + k0 + c;
        int4 o0, o1;
        o0.x = pack2(h[0], h[1]);   o0.y = pack2(h[2], h[3]);
        o0.z = pack2(h[4], h[5]);   o0.w = pack2(h[6], h[7]);
        o1.x = pack2(h[8], h[9]);   o1.y = pack2(h[10], h[11]);
        o1.z = pack2(h[12], h[13]); o1.w = pack2(h[14], h[15]);
        *(int4*)dst = o0;
        *(int4*)(dst + 8) = o1;
    }
}

// ---------------------------------------------------------------------------
// GEMM1 K-split mainloop: BM=BN=128, BK=32, 4 waves (2M x 2N), 256 threads,
// wave tile 64x64 (acc 4x4) -> minimum LDS traffic (1/Mw+1/Nw minimal).
// LDS: 2 x 16KB (A 8KB + B 8KB), 64B rows -> 4 blocks/CU = 16 waves/CU.
// 64B-row swizzle: LDS[row][s] holds source slot s ^ ((row>>1)&3); read
// slot = h ^ ((row>>1)&3). Bank audit: uniform 8/bank (minimum), 2-way free.
// K-split: HALF 0 = products a*aw (t<32) + a*bw k'<512 (t>=32);
//          HALF 1 = a*bw k'>=512 (t<16) + b*aw (t>=16).
// Byte maps into 4096B [a|b] rows verified to cover each product once.
// Skeleton = r8's proven 2-barrier loop with counted vmcnt(4).
// ---------------------------------------------------------------------------
template<int HALF>
__device__ __forceinline__ void g1_loop(ushort* lds, int m0, int n0, int tid,
                                        f32x4 (&acc)[4][4]) {
    constexpr int NT = 48;
    const int l = tid & 63, wid = tid >> 6;
    const int wm = wid >> 1, wn = wid & 1;
    // staging addressing (row = tid>>2, 4 x 16B slots per 64B row)
    const int srow  = tid >> 2;                              // 0..63
    const int sslot = ((tid & 3) ^ ((tid >> 3) & 3)) << 4;   // pre-swizzled src slot
    const char* gA = (const char*)(g_xs + (size_t)m0 * 2048);
    const char* gB = (const char*)(g_WpT + (size_t)n0 * 2048);
    // frag-read addressing
    const int l15 = l & 15;
    const int slotp = (((l >> 4) ^ ((l15 >> 1) & 3)) << 4);
    const char* pA = (const char*)lds + (wm * 64 + l15) * 64 + slotp;
    const char* pB = (const char*)lds + 8192 + (wn * 64 + l15) * 64 + slotp;

    #define AOFFk(T) (HALF == 0 ? ((T) < 32 ? (T) * 64 : ((T) - 32) * 64)            \
                                : ((T) < 16 ? 1024 + (T) * 64 : 2048 + ((T) - 16) * 64))
    #define BOFFk(T) (HALF == 0 ? ((T) < 32 ? (T) * 64 : 2048 + ((T) - 32) * 64)     \
                                : ((T) < 16 ? 3072 + (T) * 64 : ((T) - 16) * 64))

    #define STAGE1(T, BUF) do {                                                      \
        const int ao_ = AOFFk(T) + sslot, bo_ = BOFFk(T) + sslot;                    \
        char* lb_ = (char*)lds + (BUF) * 16384 + wid * 1024;                         \
        gload16(gA + (size_t)(srow)      * 4096 + ao_, lb_);                         \
        gload16(gA + (size_t)(srow + 64) * 4096 + ao_, lb_ + 4096);                  \
        gload16(gB + (size_t)(srow)      * 4096 + bo_, lb_ + 8192);                  \
        gload16(gB + (size_t)(srow + 64) * 4096 + bo_, lb_ + 12288);                 \
    } while (0)

    #define SB1 __builtin_amdgcn_sched_barrier(0)

    STAGE1(0, 0);

    #pragma unroll 2
    for (int t = 0; t < NT; ++t) {
        SB1; __builtin_amdgcn_s_barrier(); SB1;    // bar1: prior reads done
        if (t + 1 < NT) {
            STAGE1(t + 1, (t + 1) & 1);
            asm volatile("s_waitcnt vmcnt(4)" ::: "memory");   // tile t landed
        } else {
            asm volatile("s_waitcnt vmcnt(0)" ::: "memory");
        }
        SB1; __builtin_amdgcn_s_barrier(); SB1;    // bar2: publish tile t

        const int bo = (t & 1) * 16384;
        f16x8 Aa[4], Bb[4];
        #pragma unroll
        for (int i = 0; i < 4; ++i) Aa[i] = *(const f16x8*)(pA + bo + i * 1024);
        #pragma unroll
        for (int j = 0; j < 4; ++j) Bb[j] = *(const f16x8*)(pB + bo + j * 1024);
        __builtin_amdgcn_s_setprio(1);
        #pragma unroll
        for (int i = 0; i < 4; ++i)
            #pragma unroll
            for (int j = 0; j < 4; ++j)
                acc[i][j] = __builtin_amdgcn_mfma_f32_16x16x32_f16(
                    Aa[i], Bb[j], acc[i][j], 0, 0, 0);
        __builtin_amdgcn_s_setprio(0);
    }
    #undef STAGE1
    #undef SB1
    #undef AOFFk
    #undef BOFFk
}

// grid 1024 = 64 M-tiles x 8 N-tiles x 2 K-halves; bid&7 = XCD.
__global__ __launch_bounds__(256, 4) void gemm1ks() {
    __shared__ ushort lds[2 * 8192];   // 32 KB
    const int tid = threadIdx.x;
    const int bid = blockIdx.x;
    const int xcd = bid & 7;
    const int idx = bid >> 3;              // 0..127
    const int m0 = (xcd * 8 + (idx >> 4)) * 128;
    const int rest = idx & 15;
    const int n0 = (rest >> 1) * 128;
    const int half = rest & 1;

    f32x4 acc[4][4];
    #pragma unroll
    for (int i = 0; i < 4; ++i)
        #pragma unroll
        for (int j = 0; j < 4; ++j) acc[i][j] = (f32x4){0.f, 0.f, 0.f, 0.f};

    if (half == 0) g1_loop<0>(lds, m0, n0, tid, acc);
    else           g1_loop<1>(lds, m0, n0, tid, acc);

    float* pout = (half == 0) ? g_p0 : g_p1;
    const int l = tid & 63, wid = tid >> 6;
    const int wm = wid >> 1, wn = wid & 1;
    const int r4 = (l >> 4) * 4;
    const int cn = l & 15;
    #pragma unroll
    for (int i = 0; i < 4; ++i) {
        const int mg = m0 + wm * 64 + i * 16 + r4;
        const int bidx = mg >> 11;
        const int sg = mg & 2047;
        #pragma unroll
        for (int jj = 0; jj < 4; ++jj) {
            const int ng = n0 + wn * 64 + jj * 16 + cn;
            *(f32x4*)(pout + ((size_t)bidx * HN_ + ng) * S_ + sg) = acc[i][jj];
        }
    }
}

// ---------------------------------------------------------------------------
// Kuramoto + partial combine: ph = pi*tanh((p0+p1)*2^-24 + bias), then 10
// iterations in registers (verified body), write fp16 [b][hn][s].
// ---------------------------------------------------------------------------
__global__ __launch_bounds__(256) void kuramoto2(const int* __restrict__ mask,
                                                 const float* __restrict__ natf,
                                                 const float* __restrict__ coup,
                                                 const float* __restrict__ bias) {
    const int wave = blockIdx.x * 4 + (threadIdx.x >> 6);
    const int lane = threadIdx.x & 63;
    const int b = wave >> 10;
    const int hn = wave & 1023;
    const int h = hn >> 7;

    const float wf = natf[hn];
    const float K = coup[h];
    const float bb = bias[hn];

    const float* p0 = g_p0 + ((size_t)b * HN_ + hn) * S_;
    const float* p1 = g_p1 + ((size_t)b * HN_ + hn) * S_;

    float ph[32];
    #pragma unroll
    for (int i = 0; i < 8; ++i) {
        float4 v0 = *(const float4*)(p0 + i * 256 + lane * 4);
        float4 v1 = *(const float4*)(p1 + i * 256 + lane * 4);
        ph[4 * i + 0] = PI_ * tanhf(fmaf(v0.x + v1.x, INVSC2_, bb));
        ph[4 * i + 1] = PI_ * tanhf(fmaf(v0.y + v1.y, INVSC2_, bb));
        ph[4 * i + 2] = PI_ * tanhf(fmaf(v0.z + v1.z, INVSC2_, bb));
        ph[4 * i + 3] = PI_ * tanhf(fmaf(v0.w + v1.w, INVSC2_, bb));
    }

    const int* mb = mask + b * S_;
    unsigned mbits = 0;
    #pragma unroll
    for (int i = 0; i < 8; ++i) {
        int4 mv = *(const int4*)(mb + i * 256 + lane * 4);
        mbits |= (mv.x != 0 ? 1u : 0u) << (4 * i + 0);
        mbits |= (mv.y != 0 ? 1u : 0u) << (4 * i + 1);
        mbits |= (mv.z != 0 ? 1u : 0u) << (4 * i + 2);
        mbits |= (mv.w != 0 ? 1u : 0u) << (4 * i + 3);
    }

    for (int it = 0; it < ITERS_; ++it) {
        float s[32], c[32];
        float ls = 0.f, lc = 0.f;
        #pragma unroll
        for (int i = 0; i < 32; ++i) {
            s[i] = __sinf(ph[i]);
            c[i] = __cosf(ph[i]);
            const float mf = (float)((mbits >> i) & 1u);
            ls = fmaf(mf, s[i], ls);
            lc = fmaf(mf, c[i], lc);
        }
        #pragma unroll
        for (int off = 32; off; off >>= 1) {
            ls += __shfl_xor(ls, off);
            lc += __shfl_xor(lc, off);
        }
        const float ms = ls * (1.f / 2048.f);
        const float mc = lc * (1.f / 2048.f);
        #pragma unroll
        for (int i = 0; i < 32; ++i) {
            const float dth = fmaf(K, fmaf(s[i], mc, -c[i] * ms), wf);
            float t = fmaf(DT_, dth, ph[i]) + PI_;
            t -= TWOPI_ * floorf(t * INV2PI_);
            ph[i] = t - PI_;
        }
    }

    ushort* ob = g_phh + ((size_t)b * HN_ + hn) * S_;
    #pragma unroll
    for (int i = 0; i < 8; ++i) {
        ushort4 o;
        o.x = f2h(ph[4 * i + 0]); o.y = f2h(ph[4 * i + 1]);
        o.z = f2h(ph[4 * i + 2]); o.w = f2h(ph[4 * i + 3]);
        *(ushort4*)(ob + i * 256 + lane * 4) = o;
    }
}

// ---------------------------------------------------------------------------
// g_phh [b][hn][s] fp16 -> g_phT [(b,s)][hn] fp16  (64x64 tiles, unchanged)
// ---------------------------------------------------------------------------
__global__ __launch_bounds__(256) void transpose_ph() {
    __shared__ ushort t[64][72];
    const int b = blockIdx.z;
    const int h0 = blockIdx.y * 64;
    const int s0 = blockIdx.x * 64;
    const int r = threadIdx.x >> 2;
    const int c = (threadIdx.x & 3) * 16;
    const ushort* src = g_phh + ((size_t)b * HN_ + h0 + r) * S_ + s0 + c;
    *(int4*)&t[r][c] = *(const int4*)src;
    *(int4*)&t[r][c + 8] = *(const int4*)(src + 8);
    __syncthreads();
    ushort o[16];
    #pragma unroll
    for (int j = 0; j < 16; ++j) o[j] = t[c + j][r];
    ushort* dst = g_phT + ((size_t)(b * S_ + s0 + r)) * HN_ + h0 + c;
    int4 o0, o1;
    o0.x = pack2(o[0], o[1]);   o0.y = pack2(o[2], o[3]);
    o0.z = pack2(o[4], o[5]);   o0.w = pack2(o[6], o[7]);
    o1.x = pack2(o[8], o[9]);   o1.y = pack2(o[10], o[11]);
    o1.z = pack2(o[12], o[13]); o1.w = pack2(o[14], o[15]);
    *(int4*)dst = o0;
    *(int4*)(dst + 8) = o1;
}

// ---------------------------------------------------------------------------
// GEMM3 (r8's proven structure): BM=BN=128, BK=64, 8 waves (2M x 4N),
// 512 thr, wave 64x32, 128B-row swizzle, vmcnt(4), LDS 64KB, grid 512.
// ---------------------------------------------------------------------------
__device__ __forceinline__ void g3_loop(ushort* lds, int m0, int n0, int tid,
                                        f32x4 (&acc)[4][2]) {
    constexpr int NT = 16;
    const int l = tid & 63, wid = tid >> 6;
    const int wm = wid >> 2, wn = wid & 3;
    const int r8g  = l >> 3;
    const int swzo = ((l & 7) * 16) ^ (r8g << 4);
    const char* gA = (const char*)(g_phT + (size_t)m0 * 1024);
    const char* gB = (const char*)(g_WoT + (size_t)n0 * 1024);
    const int l15 = l & 15;
    const int xk  = (l15 & 7) << 4;
    const int sl0 = ((l >> 4) * 16) ^ xk;
    const int sl1 = (64 + (l >> 4) * 16) ^ xk;
    const char* pA = (const char*)lds + (wm * 64 + l15) * 128;
    const char* pB = (const char*)lds + 16384 + (wn * 32 + l15) * 128;

    #define STAGE3(T, BUF) do {                                                    \
        const size_t gb_ = (size_t)(T) * 128 + swzo;                               \
        char* lb_ = (char*)lds + (BUF) * 32768 + wid * 2048;                       \
        gload16(gA + (size_t)(wid * 16 + r8g)     * 2048 + gb_, lb_);              \
        gload16(gA + (size_t)(wid * 16 + 8 + r8g) * 2048 + gb_, lb_ + 1024);       \
        gload16(gB + (size_t)(wid * 16 + r8g)     * 2048 + gb_, lb_ + 16384);      \
        gload16(gB + (size_t)(wid * 16 + 8 + r8g) * 2048 + gb_, lb_ + 16384 + 1024); \
    } while (0)

    #define SB3 __builtin_amdgcn_sched_barrier(0)

    STAGE3(0, 0);

    #pragma unroll 2
    for (int t = 0; t < NT; ++t) {
        SB3; __builtin_amdgcn_s_barrier(); SB3;
        if (t + 1 < NT) {
            STAGE3(t + 1, (t + 1) & 1);
            asm volatile("s_waitcnt vmcnt(4)" ::: "memory");
        } else {
            asm volatile("s_waitcnt vmcnt(0)" ::: "memory");
        }
        SB3; __builtin_amdgcn_s_barrier(); SB3;

        const int bo = (t & 1) << 15;
        f16x8 Aa[4][2], Bb[2][2];
        #pragma unroll
        for (int i = 0; i < 4; ++i) {
            Aa[i][0] = *(const f16x8*)(pA + bo + i * 2048 + sl0);
            Aa[i][1] = *(const f16x8*)(pA + bo + i * 2048 + sl1);
        }
        #pragma unroll
        for (int j = 0; j < 2; ++j) {
            Bb[j][0] = *(const f16x8*)(pB + bo + j * 2048 + sl0);
            Bb[j][1] = *(const f16x8*)(pB + bo + j * 2048 + sl1);
        }
        __builtin_amdgcn_s_setprio(1);
        #pragma unroll
        for (int ks = 0; ks < 2; ++ks)
            #pragma unroll
            for (int i = 0; i < 4; ++i)
                #pragma unroll
                for (int j = 0; j < 2; ++j)
                    acc[i][j] = __builtin_amdgcn_mfma_f32_16x16x32_f16(
                        Aa[i][ks], Bb[j][ks], acc[i][j], 0, 0, 0);
        __builtin_amdgcn_s_setprio(0);
    }
    #undef STAGE3
    #undef SB3
}

__global__ __launch_bounds__(512, 4) void gemm3(const float* __restrict__ bias,
                                                float* __restrict__ Y) {
    __shared__ ushort lds[2 * 16384];   // 64 KB
    const int tid = threadIdx.x;
    const int bid = blockIdx.x;
    const int xcd = bid & 7;
    const int idx = bid >> 3;              // 0..63
    const int m0 = (xcd * 8 + (idx >> 3)) * 128;
    const int n0 = (idx & 7) * 128;

    f32x4 acc[4][2];
    #pragma unroll
    for (int i = 0; i < 4; ++i)
        #pragma unroll
        for (int j = 0; j < 2; ++j) acc[i][j] = (f32x4){0.f, 0.f, 0.f, 0.f};

    g3_loop(lds, m0, n0, tid, acc);

    const int l = tid & 63, wid = tid >> 6;
    const int wm = wid >> 2, wn = wid & 3;
    const int r4 = (l >> 4) * 4;
    const int cn = l & 15;
    #pragma unroll
    for (int i = 0; i < 4; ++i) {
        const int mg = m0 + wm * 64 + i * 16 + r4;
        #pragma unroll
        for (int jj = 0; jj < 2; ++jj) {
            const int ng = n0 + wn * 32 + jj * 16 + cn;
            const float bb = bias[ng];
            #pragma unroll
            for (int r = 0; r < 4; ++r)
                Y[(size_t)(mg + r) * D_ + ng] = acc[i][jj][r] + bb;
        }
    }
}

extern "C" void kernel_launch(void* const* d_in, const int* in_sizes, int n_in,
                              void* d_out, int out_size, void* d_ws, size_t ws_size,
                              hipStream_t stream) {
    const float* x    = (const float*)d_in[0];
    const int*   mask = (const int*)d_in[1];
    const float* Wp   = (const float*)d_in[2];
    const float* bp   = (const float*)d_in[3];
    const float* natf = (const float*)d_in[4];
    const float* coup = (const float*)d_in[5];
    const float* Wo   = (const float*)d_in[6];
    const float* bo   = (const float*)d_in[7];
    float* y = (float*)d_out;

    prep        <<<dim3(2560),       256, 0, stream>>>(x, Wp, Wo);
    gemm1ks     <<<dim3(1024),       256, 0, stream>>>();
    kuramoto2   <<<dim3(1024),       256, 0, stream>>>(mask, natf, coup, bp);
    transpose_ph<<<dim3(32, 16, 4),  256, 0, stream>>>();
    gemm3       <<<dim3(512),        512, 0, stream>>>(bo, y);
}

// Round 13
// 159.271 us; speedup vs baseline: 1.2091x; 1.1815x over previous
//
#include <hip/hip_runtime.h>
#include <math.h>

#define S_ 2048
#define D_ 1024
#define HN_ 1024
#define B_ 4
#define M_ 8192
#define ITERS_ 10
#define DT_ 0.1f
#define PI_ 3.14159265358979323846f
#define TWOPI_ 6.28318530717958647692f
#define INV2PI_ 0.15915494309189533577f
#define SCALE_ 4096.0f
#define INVSC2_ (1.0f / 16777216.0f)   // 2^-24

typedef __attribute__((ext_vector_type(8))) _Float16 f16x8;
typedef __attribute__((ext_vector_type(4))) float f32x4;

// static scratch
__device__ __align__(16) ushort g_xs [(size_t)M_ * 2048];   // x split [a|b] fp16, scaled 4096
__device__ __align__(16) ushort g_WpT[(size_t)HN_ * 2048];  // Wp^T split [a|b] fp16, scaled
__device__ __align__(16) ushort g_WoT[(size_t)D_ * 1024];   // Wo^T fp16 [d][hn]
__device__ __align__(16) float  g_ph [(size_t)B_ * HN_ * S_]; // phases f32 [b][hn][s]
__device__ __align__(16) ushort g_phh[(size_t)B_ * HN_ * S_]; // final phases fp16
__device__ __align__(16) ushort g_phT[(size_t)M_ * HN_];      // phases fp16 [(b,s)][hn]

__device__ __forceinline__ ushort f2h(float f) {
    union { _Float16 h; ushort u; } v; v.h = (_Float16)f; return v.u;
}
__device__ __forceinline__ void split2s(float x, ushort& A, ushort& Bc) {
    const float xs = x * SCALE_;
    union { _Float16 h; ushort u; } va, vb;
    va.h = (_Float16)xs;
    const float r = xs - (float)va.h;   // exact
    vb.h = (_Float16)r;
    A = va.u; Bc = vb.u;
}
__device__ __forceinline__ void gload16(const void* g, void* l) {
    __builtin_amdgcn_global_load_lds(
        (const __attribute__((address_space(1))) void*)g,
        (__attribute__((address_space(3))) void*)l, 16, 0, 0);
}
__device__ __forceinline__ int pack2(ushort a, ushort b) {
    return (int)(unsigned)a | ((int)(unsigned)b << 16);
}

// ---------------------------------------------------------------------------
// Merged prep (r12-verified): blocks [0,2048) = split_x (4 float4/thread);
//   [2048,2304) = Wp transpose+split ; [2304,2560) = Wo transpose+cast.
// ---------------------------------------------------------------------------
__global__ __launch_bounds__(256) void prep(const float* __restrict__ X,
                                            const float* __restrict__ Wp,
                                            const float* __restrict__ Wo) {
    __shared__ float t[64][68];
    const int bid = blockIdx.x;
    const int tid = threadIdx.x;
    if (bid < 2048) {
        #pragma unroll
        for (int p = 0; p < 4; ++p) {
            const int idx = bid * 1024 + p * 256 + tid;
            const float4 v = ((const float4*)X)[idx];
            const int m  = idx >> 8;
            const int k4 = (idx & 255) * 4;
            ushort a[4], b[4];
            split2s(v.x, a[0], b[0]);
            split2s(v.y, a[1], b[1]);
            split2s(v.z, a[2], b[2]);
            split2s(v.w, a[3], b[3]);
            ushort* row = g_xs + (size_t)m * 2048 + k4;
            int2 oa; oa.x = pack2(a[0], a[1]); oa.y = pack2(a[2], a[3]);
            int2 ob; ob.x = pack2(b[0], b[1]); ob.y = pack2(b[2], b[3]);
            *(int2*)(row)        = oa;
            *(int2*)(row + 1024) = ob;
        }
        return;
    }
    const int wb   = bid - 2048;
    const bool isWp = (wb < 256);
    const int g  = isWp ? wb : wb - 256;
    const int k0 = (g >> 4) * 64;
    const int n0 = (g & 15) * 64;
    const int r = tid >> 2;
    const int c = (tid & 3) * 16;
    const float* src = (isWp ? Wp : Wo) + (size_t)(k0 + r) * 1024 + n0 + c;
    #pragma unroll
    for (int q = 0; q < 4; ++q)
        *(float4*)&t[r][c + 4 * q] = ((const float4*)src)[q];
    __syncthreads();
    if (isWp) {
        ushort ha[16], hb[16];
        #pragma unroll
        for (int j = 0; j < 16; ++j)
            split2s(t[c + j][r], ha[j], hb[j]);
        int4 a0, a1, b0, b1;
        a0.x = pack2(ha[0], ha[1]);   a0.y = pack2(ha[2], ha[3]);
        a0.z = pack2(ha[4], ha[5]);   a0.w = pack2(ha[6], ha[7]);
        a1.x = pack2(ha[8], ha[9]);   a1.y = pack2(ha[10], ha[11]);
        a1.z = pack2(ha[12], ha[13]); a1.w = pack2(ha[14], ha[15]);
        b0.x = pack2(hb[0], hb[1]);   b0.y = pack2(hb[2], hb[3]);
        b0.z = pack2(hb[4], hb[5]);   b0.w = pack2(hb[6], hb[7]);
        b1.x = pack2(hb[8], hb[9]);   b1.y = pack2(hb[10], hb[11]);
        b1.z = pack2(hb[12], hb[13]); b1.w = pack2(hb[14], hb[15]);
        ushort* dst = g_WpT + (size_t)(n0 + r) * 2048 + k0 + c;
        *(int4*)(dst)        = a0; *(int4*)(dst + 8)    = a1;
        *(int4*)(dst + 1024) = b0; *(int4*)(dst + 1032) = b1;
    } else {
        ushort h[16];
        #pragma unroll
        for (int j = 0; j < 16; ++j) h[j] = f2h(t[c + j][r]);
        ushort* dst = g_WoT + (size_t)(n0 + r) * 1024 + k0 + c;
        int4 o0, o1;
        o0.x = pack2(h[0], h[1]);   o0.y = pack2(h[2], h[3]);
        o0.z = pack2(h[4], h[5]);   o0.w = pack2(h[6], h[7]);
        o1.x = pack2(h[8], h[9]);   o1.y = pack2(h[10], h[11]);
        o1.z = pack2(h[12], h[13]); o1.w = pack2(h[14], h[15]);
        *(int4*)dst = o0;
        *(int4*)(dst + 8) = o1;
    }
}

// ---------------------------------------------------------------------------
// MFMA main loop (r8's PROVEN skeleton, the 84-us optimum): BM=BN=128, BK=64,
// 8 waves (2M x 4N), 512 threads, wave 64x32 (acc 4x2). LDS 2x32KB double
// buffer = 64KB -> 2 blocks/CU = 16 waves/CU. 2 raw s_barriers per K-tile,
// counted vmcnt(4), 128B-row T2 swizzle both-sides (conflicts 0).
// r11-verified K-dedup [a|b] maps (KROW=2048): product order a*aw, a*bw,
// b*aw -- accumulation order identical to the verified r3+ path.
// ---------------------------------------------------------------------------
template<int NT, int SPLIT>
__device__ __forceinline__ void gemm_mainloop(const ushort* __restrict__ A,
                                              const ushort* __restrict__ Bm,
                                              ushort* lds,
                                              int m0, int n0, int wid, int l,
                                              f32x4 (&acc)[4][2]) {
    constexpr int KROW = SPLIT ? 2048 : 1024;      // stored row elems
    const int r8   = l >> 3;                       // 0..7
    const int swzo = ((l & 7) * 16) ^ (r8 << 4);   // inverse-swizzled source byte
    const char* gA = (const char*)(A + (size_t)m0 * KROW);
    const char* gB = (const char*)(Bm + (size_t)n0 * KROW);

    const int wm = wid >> 2, wn = wid & 3;
    const int l15 = l & 15;
    const int xk  = (l15 & 7) << 4;
    const int sl0 = (((l >> 4) * 16)) ^ xk;        // ks=0 slot
    const int sl1 = (64 + ((l >> 4) * 16)) ^ xk;   // ks=1 slot
    const char* pA = (const char*)lds + (wm * 64 + l15) * 128;
    const char* pB = (const char*)lds + 16384 + (wn * 32 + l15) * 128;

    // byte offsets of K-tile T within the stored 4096B [a|b] row (r11-verified)
    #define AOFF(T) ((size_t)(SPLIT ? ((T) < 32 ? ((T) & 15) * 128 : 2048 + ((T) - 32) * 128) \
                                    : (T) * 128))
    #define BOFF(T) ((size_t)(SPLIT ? ((T) < 16 ? (T) * 128                                   \
                                     : ((T) < 32 ? 2048 + ((T) - 16) * 128                    \
                                                 : ((T) - 32) * 128))                         \
                                    : (T) * 128))

    #define STAGE(T, BUF) do {                                                    \
        const size_t ao_ = AOFF(T) + swzo, bo_ = BOFF(T) + swzo;                  \
        char* lb_ = (char*)lds + (BUF) * 32768 + wid * 2048;                      \
        gload16(gA + (size_t)(wid * 16 + r8)     * (KROW * 2) + ao_, lb_);        \
        gload16(gA + (size_t)(wid * 16 + 8 + r8) * (KROW * 2) + ao_, lb_ + 1024); \
        gload16(gB + (size_t)(wid * 16 + r8)     * (KROW * 2) + bo_, lb_ + 16384);\
        gload16(gB + (size_t)(wid * 16 + 8 + r8) * (KROW * 2) + bo_, lb_ + 16384 + 1024); \
    } while (0)

    STAGE(0, 0);

    #pragma unroll 2
    for (int t = 0; t < NT; ++t) {
        __builtin_amdgcn_sched_barrier(0);
        __builtin_amdgcn_s_barrier();              // bar1: all prior reads done
        __builtin_amdgcn_sched_barrier(0);
        if (t + 1 < NT) {
            STAGE(t + 1, (t + 1) & 1);
            asm volatile("s_waitcnt vmcnt(4)" ::: "memory");   // tile t landed
        } else {
            asm volatile("s_waitcnt vmcnt(0)" ::: "memory");
        }
        __builtin_amdgcn_sched_barrier(0);
        __builtin_amdgcn_s_barrier();              // bar2: publish tile t
        __builtin_amdgcn_sched_barrier(0);

        const int bo = (t & 1) << 15;
        f16x8 Aa[4][2], Bb[2][2];
        #pragma unroll
        for (int i = 0; i < 4; ++i) {
            Aa[i][0] = *(const f16x8*)(pA + bo + i * 2048 + sl0);
            Aa[i][1] = *(const f16x8*)(pA + bo + i * 2048 + sl1);
        }
        #pragma unroll
        for (int j = 0; j < 2; ++j) {
            Bb[j][0] = *(const f16x8*)(pB + bo + j * 2048 + sl0);
            Bb[j][1] = *(const f16x8*)(pB + bo + j * 2048 + sl1);
        }
        __builtin_amdgcn_s_setprio(1);
        #pragma unroll
        for (int ks = 0; ks < 2; ++ks)
            #pragma unroll
            for (int i = 0; i < 4; ++i)
                #pragma unroll
                for (int j = 0; j < 2; ++j)
                    acc[i][j] = __builtin_amdgcn_mfma_f32_16x16x32_f16(
                        Aa[i][ks], Bb[j][ks], acc[i][j], 0, 0, 0);
        __builtin_amdgcn_s_setprio(0);
    }
    #undef STAGE
    #undef AOFF
    #undef BOFF
}

// 512 blocks: per XCD 8 M-panels x 8 N-panels (A fetched once chip-wide)
__device__ __forceinline__ void tile_map(int bid, int& m0, int& n0) {
    const int xcd = bid & 7;
    const int idx = bid >> 3;              // 0..63
    m0 = (xcd * 8 + (idx >> 3)) * 128;     // 64 M-tiles
    n0 = (idx & 7) * 128;                  // 8 N-tiles
}

// GEMM1: g_xs x g_WpT (dedup K=3072) -> pi*tanh(acc*2^-24 + bias) -> g_ph[b][n][s]
__global__ __launch_bounds__(512, 4) void gemm1(const float* __restrict__ bias) {
    __shared__ ushort lds[2 * 16384];   // 64 KB
    const int tid = threadIdx.x;
    const int wid = tid >> 6, l = tid & 63;
    int m0, n0;
    tile_map(blockIdx.x, m0, n0);
    const int wm = wid >> 2, wn = wid & 3;

    f32x4 acc[4][2];
    #pragma unroll
    for (int i = 0; i < 4; ++i)
        #pragma unroll
        for (int j = 0; j < 2; ++j) acc[i][j] = (f32x4){0.f, 0.f, 0.f, 0.f};

    gemm_mainloop<48, 1>(g_xs, g_WpT, lds, m0, n0, wid, l, acc);

    const int r4 = (l >> 4) * 4;
    const int cn = l & 15;
    #pragma unroll
    for (int i = 0; i < 4; ++i) {
        const int mg = m0 + wm * 64 + i * 16 + r4;
        const int bidx = mg >> 11;
        const int sg = mg & 2047;
        #pragma unroll
        for (int jj = 0; jj < 2; ++jj) {
            const int ng = n0 + wn * 32 + jj * 16 + cn;
            const float bb = bias[ng];
            float4 o;
            o.x = PI_ * tanhf(fmaf(acc[i][jj][0], INVSC2_, bb));
            o.y = PI_ * tanhf(fmaf(acc[i][jj][1], INVSC2_, bb));
            o.z = PI_ * tanhf(fmaf(acc[i][jj][2], INVSC2_, bb));
            o.w = PI_ * tanhf(fmaf(acc[i][jj][3], INVSC2_, bb));
            *(float4*)(g_ph + ((size_t)bidx * HN_ + ng) * S_ + sg) = o;
        }
    }
}

// GEMM3: g_phT x g_WoT + bias -> Y [8192][1024] f32 (r8 verbatim)
__global__ __launch_bounds__(512, 4) void gemm3(const float* __restrict__ bias,
                                                float* __restrict__ Y) {
    __shared__ ushort lds[2 * 16384];   // 64 KB
    const int tid = threadIdx.x;
    const int wid = tid >> 6, l = tid & 63;
    int m0, n0;
    tile_map(blockIdx.x, m0, n0);
    const int wm = wid >> 2, wn = wid & 3;

    f32x4 acc[4][2];
    #pragma unroll
    for (int i = 0; i < 4; ++i)
        #pragma unroll
        for (int j = 0; j < 2; ++j) acc[i][j] = (f32x4){0.f, 0.f, 0.f, 0.f};

    gemm_mainloop<16, 0>(g_phT, g_WoT, lds, m0, n0, wid, l, acc);

    const int r4 = (l >> 4) * 4;
    const int cn = l & 15;
    #pragma unroll
    for (int i = 0; i < 4; ++i) {
        const int mg = m0 + wm * 64 + i * 16 + r4;
        #pragma unroll
        for (int jj = 0; jj < 2; ++jj) {
            const int ng = n0 + wn * 32 + jj * 16 + cn;
            const float bb = bias[ng];
            #pragma unroll
            for (int r = 0; r < 4; ++r)
                Y[(size_t)(mg + r) * D_ + ng] = acc[i][jj][r] + bb;
        }
    }
}

// ---------------------------------------------------------------------------
// Kuramoto (r8 verbatim): one wave per (b, hn), 10 iters in registers.
// ---------------------------------------------------------------------------
__global__ __launch_bounds__(256) void kuramoto(const int* __restrict__ mask,
                                                const float* __restrict__ natf,
                                                const float* __restrict__ coup) {
    const int wave = blockIdx.x * 4 + (threadIdx.x >> 6);
    const int lane = threadIdx.x & 63;
    const int b = wave >> 10;
    const int hn = wave & 1023;
    const int h = hn >> 7;

    const float wf = natf[hn];
    const float K = coup[h];

    const float* base = g_ph + ((size_t)b * HN_ + hn) * S_;

    float ph[32];
    #pragma unroll
    for (int i = 0; i < 8; ++i) {
        float4 v = *(const float4*)(base + i * 256 + lane * 4);
        ph[4 * i + 0] = v.x; ph[4 * i + 1] = v.y;
        ph[4 * i + 2] = v.z; ph[4 * i + 3] = v.w;
    }

    const int* mb = mask + b * S_;
    unsigned mbits = 0;
    #pragma unroll
    for (int i = 0; i < 8; ++i) {
        int4 mv = *(const int4*)(mb + i * 256 + lane * 4);
        mbits |= (mv.x != 0 ? 1u : 0u) << (4 * i + 0);
        mbits |= (mv.y != 0 ? 1u : 0u) << (4 * i + 1);
        mbits |= (mv.z != 0 ? 1u : 0u) << (4 * i + 2);
        mbits |= (mv.w != 0 ? 1u : 0u) << (4 * i + 3);
    }

    for (int it = 0; it < ITERS_; ++it) {
        float s[32], c[32];
        float ls = 0.f, lc = 0.f;
        #pragma unroll
        for (int i = 0; i < 32; ++i) {
            s[i] = __sinf(ph[i]);
            c[i] = __cosf(ph[i]);
            const float mf = (float)((mbits >> i) & 1u);
            ls = fmaf(mf, s[i], ls);
            lc = fmaf(mf, c[i], lc);
        }
        #pragma unroll
        for (int off = 32; off; off >>= 1) {
            ls += __shfl_xor(ls, off);
            lc += __shfl_xor(lc, off);
        }
        const float ms = ls * (1.f / 2048.f);
        const float mc = lc * (1.f / 2048.f);
        #pragma unroll
        for (int i = 0; i < 32; ++i) {
            const float dth = fmaf(K, fmaf(s[i], mc, -c[i] * ms), wf);
            float t = fmaf(DT_, dth, ph[i]) + PI_;
            t -= TWOPI_ * floorf(t * INV2PI_);
            ph[i] = t - PI_;
        }
    }

    ushort* ob = g_phh + ((size_t)b * HN_ + hn) * S_;
    #pragma unroll
    for (int i = 0; i < 8; ++i) {
        ushort4 o;
        o.x = f2h(ph[4 * i + 0]); o.y = f2h(ph[4 * i + 1]);
        o.z = f2h(ph[4 * i + 2]); o.w = f2h(ph[4 * i + 3]);
        *(ushort4*)(ob + i * 256 + lane * 4) = o;
    }
}

// ---------------------------------------------------------------------------
// g_phh [b][hn][s] fp16 -> g_phT [(b,s)][hn] fp16  (64x64 tiles, unchanged)
// ---------------------------------------------------------------------------
__global__ __launch_bounds__(256) void transpose_ph() {
    __shared__ ushort t[64][72];
    const int b = blockIdx.z;
    const int h0 = blockIdx.y * 64;
    const int s0 = blockIdx.x * 64;
    const int r = threadIdx.x >> 2;
    const int c = (threadIdx.x & 3) * 16;
    const ushort* src = g_phh + ((size_t)b * HN_ + h0 + r) * S_ + s0 + c;
    *(int4*)&t[r][c] = *(const int4*)src;
    *(int4*)&t[r][c + 8] = *(const int4*)(src + 8);
    __syncthreads();
    ushort o[16];
    #pragma unroll
    for (int j = 0; j < 16; ++j) o[j] = t[c + j][r];
    ushort* dst = g_phT + ((size_t)(b * S_ + s0 + r)) * HN_ + h0 + c;
    int4 o0, o1;
    o0.x = pack2(o[0], o[1]);   o0.y = pack2(o[2], o[3]);
    o0.z = pack2(o[4], o[5]);   o0.w = pack2(o[6], o[7]);
    o1.x = pack2(o[8], o[9]);   o1.y = pack2(o[10], o[11]);
    o1.z = pack2(o[12], o[13]); o1.w = pack2(o[14], o[15]);
    *(int4*)dst = o0;
    *(int4*)(dst + 8) = o1;
}

extern "C" void kernel_launch(void* const* d_in, const int* in_sizes, int n_in,
                              void* d_out, int out_size, void* d_ws, size_t ws_size,
                              hipStream_t stream) {
    const float* x    = (const float*)d_in[0];
    const int*   mask = (const int*)d_in[1];
    const float* Wp   = (const float*)d_in[2];
    const float* bp   = (const float*)d_in[3];
    const float* natf = (const float*)d_in[4];
    const float* coup = (const float*)d_in[5];
    const float* Wo   = (const float*)d_in[6];
    const float* bo   = (const float*)d_in[7];
    float* y = (float*)d_out;

    prep        <<<dim3(2560),      256, 0, stream>>>(x, Wp, Wo);
    gemm1       <<<dim3(512),       512, 0, stream>>>(bp);
    kuramoto    <<<dim3(1024),      256, 0, stream>>>(mask, natf, coup);
    transpose_ph<<<dim3(32, 16, 4), 256, 0, stream>>>();
    gemm3       <<<dim3(512),       512, 0, stream>>>(bo, y);
}